// Round 10
// baseline (97.879 us; speedup 1.0000x reference)
//
#include <hip/hip_runtime.h>

constexpr int TN   = 100000;
constexpr int NCH  = 2500;
constexpr int CLEN = 40;            // NCH*CLEN == TN
constexpr int WARM = 32;            // warm-up steps (contraction forgets init)
constexpr int WPB  = 4;             // waves per block
constexpr int NBLK = NCH / WPB;     // 625
constexpr int MAXS = WARM + CLEN;   // 72

constexpr float LOG2E = 1.4426950408889634f;
constexpr float PI_F  = 3.1415926f;

// DPP row-rotate by N within 16-lane rows (direction auto-detected at runtime)
#define ROR(src, N) __int_as_float(__builtin_amdgcn_mov_dpp( \
    __float_as_int(src), 0x120 + (N), 0xF, 0xF, false))

#define ROTS(SRC, R)                                                          \
  float R##1 = ROR(SRC, 1),  R##2 = ROR(SRC, 2),  R##3 = ROR(SRC, 3),         \
        R##4 = ROR(SRC, 4),  R##5 = ROR(SRC, 5),  R##6 = ROR(SRC, 6),         \
        R##7 = ROR(SRC, 7),  R##8 = ROR(SRC, 8),  R##9 = ROR(SRC, 9),         \
        R##10 = ROR(SRC,10), R##11 = ROR(SRC,11), R##12 = ROR(SRC,12),        \
        R##13 = ROR(SRC,13), R##14 = ROR(SRC,14), R##15 = ROR(SRC,15);

// 16-FMA partial dot against rotation-ordered weights (4 chains + tree)
#define DOT16(Wr, SRC, R, dd)                                                 \
  float dd;                                                                   \
  { float q0 = Wr[0]*(SRC)  + Wr[4]*R##4;                                     \
    float q1 = Wr[1]*R##1   + Wr[5]*R##5;                                     \
    float q2 = Wr[2]*R##2   + Wr[6]*R##6;                                     \
    float q3 = Wr[3]*R##3   + Wr[7]*R##7;                                     \
    q0 += Wr[8]*R##8;   q1 += Wr[9]*R##9;                                     \
    q2 += Wr[10]*R##10; q3 += Wr[11]*R##11;                                   \
    q0 += Wr[12]*R##12; q1 += Wr[13]*R##13;                                   \
    q2 += Wr[14]*R##14; q3 += Wr[15]*R##15;                                   \
    dd = (q0 + q1) + (q2 + q3); }

// 16-lane ring reduction via rotate-adds (direction-agnostic), stays on VALU
#define RING16(v) { v += ROR(v,1); v += ROR(v,2); v += ROR(v,4); v += ROR(v,8); }

// ---------------------------------------------------------------------------
// k_main: fused prep + warm-up + loss. One wave per chunk of CLEN steps,
// warm-started WARM steps early (chunks with t0 <= WARM start exactly from pi
// at t=0; Birkhoff contraction erases the uniform init otherwise).
// K-SPLIT layout: lane l covers k-block h = l>>5 for output j = l&31.
// Step: 15 DPP rotations, 16 FMAs -> partial dot, one shfl_xor(32) combine.
// KEY CHANGE vs R9: the loss loop keeps y UNNORMALIZED (true u, periodic
// 1/y_0 rescale like warm-up). loss_t = N2/S is scale-invariant, so the
// RING16/xor/rcp reduction has no consumer in the recursion chain and
// overlaps with the next step's rotations — the serial chain is only
// rot -> FMA tree -> xor32 -> u*dot -> xor16-select.
// ---------------------------------------------------------------------------
__global__ __launch_bounds__(256, 4) void k_main(
    const float* __restrict__ obs2, const float* __restrict__ obs1,
    const float* __restrict__ mean_p, const float* __restrict__ var_p,
    const float* __restrict__ bate_p, const float* __restrict__ pi_p,
    const float* __restrict__ aij, float* __restrict__ lossbuf)
{
  const int w = threadIdx.x >> 6, lane = threadIdx.x & 63;
  const int wv = blockIdx.x * WPB + w;
  const int i  = lane & 15;
  const int h  = lane >> 5;           // k-half this lane covers
  const int j  = lane & 31;           // this lane's output index
  const int kb = h * 16;              // k-block base

  __shared__ __align__(16) float Wsh[2][32][32];   // [sel][k][j]
  __shared__ float cts[WPB][MAXS + 2];

  // --- block-cooperative prep of W, W2 into LDS (once) ---
  {
    const int tid = threadIdx.x;
    const int jj = tid & 31, ig = tid >> 5;
    float vjq  = var_p[jj];
    float i2vq = 0.5f / vjq;
    float norm = rsqrtf(2.0f * PI_F * vjq);
    float Aj   = norm * expf(mean_p[jj] * i2vq);
    float bate = bate_p[0];
#pragma unroll
    for (int m = 0; m < 4; ++m) {
      int ii = ig * 4 + m;
      float Bij = expf(-bate * mean_p[ii] * i2vq);
      float wq = aij[ii * 32 + jj] * Aj * Bij;
      Wsh[0][ii][jj] = wq;
      Wsh[1][ii][jj] = wq * Aj * Bij;
    }
  }

  // --- per-lane exponent constants (j-indexed; halves duplicate) ---
  float vj  = var_p[j];
  float i2v = 0.5f / vj;
  float s_  = i2v;
#pragma unroll
  for (int o = 1; o < 32; o <<= 1) s_ += __shfl_xor(s_, o);
  const float i2vl = i2v * LOG2E;                      // true (loss)
  const float i2vc = (i2v - s_ * 0.03125f) * LOG2E;    // centered (warm)

  // --- stage cts for this wave's range ---
  const int t0 = wv * CLEN;
  const int tw = (t0 > WARM) ? (t0 - WARM) : 0;
  const int n  = t0 + CLEN - tw;
  const int warmsteps = t0 - tw;
  {
    float bate = bate_p[0];
    for (int l = lane; l < n; l += 64)
      cts[w][l] = obs2[tw + l] - bate * obs1[tw + l];
  }
  __syncthreads();   // Wsh ready (only barrier)

  // --- rotation direction probe (ROW_ROR direction made irrelevant) ---
  int dird;
  { int p = __builtin_amdgcn_mov_dpp(i, 0x121, 0xF, 0xF, false);
    dird = (p - i) & 15; }

  // --- rotation-ordered weights for this lane's k-block, output j ---
  float Wr[16], Vr[16];
#pragma unroll
  for (int N = 0; N < 16; ++N) {
    int kk = (i + N * dird) & 15;
    Wr[N] = Wsh[0][kb + kk][j];
    Vr[N] = Wsh[1][kb + kk][j];
  }

  // ysrc layout: lane must hold y_{kb + (l&15)}; from the j-indexed y this is
  // own y when (bit4 == h), else the xor-16 partner's value.
  const bool takeT = (((lane >> 4) & 1) ^ h) != 0;

  float y = (tw == 0) ? pi_p[j] : 0.03125f;
  float t = __shfl_xor(y, 16);
  float ysrc = takeT ? t : y;

  int s = 0;
  // ---- warm-up: centered u, W-dot only, unnormalized + periodic rescale ----
  for (; s < warmsteps; ++s) {
    float ct = cts[w][s];
    float u  = exp2f(-ct * i2vc);
    ROTS(ysrc, a)
    DOT16(Wr, ysrc, a, pW)
    float dot = pW + __shfl_xor(pW, 32);
    y = u * dot;
    if ((s & 3) == 3)
      y *= __builtin_amdgcn_rcpf(__int_as_float(
             __builtin_amdgcn_readfirstlane(__float_as_int(y))));
    t = __shfl_xor(y, 16);
    ysrc = takeT ? t : y;
  }
  // ---- owned range: true u, UNNORMALIZED y; reduce runs off-chain ----
  float lossacc = 0.f;
  for (; s < n; ++s) {
    float ct = cts[w][s];
    float u  = exp2f(-ct * i2vl);
    ROTS(ysrc, a)
    DOT16(Wr, ysrc, a, pW)
    DOT16(Vr, ysrc, a, pV)
    float dotW = pW + __shfl_xor(pW, 32);
    float dotV = pV + __shfl_xor(pV, 32);
    float numj = u * dotW;             // next y (unnormalized)
    float n2j  = (u * u) * dotV;
    // --- recursion chain: only numj -> y -> ysrc ---
    y = numj;
    if ((s & 3) == 3)
      y *= __builtin_amdgcn_rcpf(__int_as_float(
             __builtin_amdgcn_readfirstlane(__float_as_int(y))));
    t = __shfl_xor(y, 16);
    ysrc = takeT ? t : y;
    // --- side-band loss reduce (no consumer in the chain) ---
    float red = h ? n2j : numj;
    RING16(red)
    red += __shfl_xor(red, 16);        // h=0 lanes: S ; h=1 lanes: N2
    float cross = __shfl_xor(red, 32);
    float S  = h ? cross : red;
    float N2 = h ? red   : cross;
    lossacc += N2 * __builtin_amdgcn_rcpf(S);
  }
  if (lane == 0) lossbuf[wv] = lossacc;
}

// ---------------------------------------------------------------------------
// Finish: sum NCH per-chunk losses -> out[0]
// ---------------------------------------------------------------------------
__global__ __launch_bounds__(256) void k_finish(const float* __restrict__ lb,
                                                float* __restrict__ out)
{
  const int tid = threadIdx.x;
  float v = 0.f;
  for (int l = tid; l < NCH; l += 256) v += lb[l];
#pragma unroll
  for (int o = 1; o < 64; o <<= 1) v += __shfl_xor(v, o);
  __shared__ float part[4];
  if ((tid & 63) == 0) part[tid >> 6] = v;
  __syncthreads();
  if (tid == 0) out[0] = part[0] + part[1] + part[2] + part[3];
}

extern "C" void kernel_launch(void* const* d_in, const int* in_sizes, int n_in,
                              void* d_out, int out_size, void* d_ws, size_t ws_size,
                              hipStream_t stream)
{
  (void)in_sizes; (void)n_in; (void)ws_size; (void)out_size;
  const float* obs2 = (const float*)d_in[0];
  const float* obs1 = (const float*)d_in[1];
  const float* mean = (const float*)d_in[2];
  const float* var  = (const float*)d_in[3];
  const float* bate = (const float*)d_in[4];
  const float* pi   = (const float*)d_in[5];
  const float* aij  = (const float*)d_in[6];
  float* lb  = (float*)d_ws;           // NCH floats, every slot written
  float* out = (float*)d_out;

  k_main  <<<NBLK, 256, 0, stream>>>(obs2, obs1, mean, var, bate, pi, aij, lb);
  k_finish<<<1,    256, 0, stream>>>(lb, out);
}

// Round 11
// 91.925 us; speedup vs baseline: 1.0648x; 1.0648x over previous
//
#include <hip/hip_runtime.h>

constexpr int TN   = 100000;
constexpr int NCH  = 4000;
constexpr int CLEN = 25;            // NCH*CLEN == TN
constexpr int WARM = 24;            // warm-up steps (contraction forgets init)
constexpr int WPB  = 4;             // waves per block
constexpr int NBLK = NCH / WPB;     // 1000
constexpr int MAXS = WARM + CLEN;   // 49

constexpr float LOG2E = 1.4426950408889634f;
constexpr float PI_F  = 3.1415926f;

// DPP row-rotate by N within 16-lane rows (direction auto-detected at runtime)
#define ROR(src, N) __int_as_float(__builtin_amdgcn_mov_dpp( \
    __float_as_int(src), 0x120 + (N), 0xF, 0xF, false))

#define ROTS(SRC, R)                                                          \
  float R##1 = ROR(SRC, 1),  R##2 = ROR(SRC, 2),  R##3 = ROR(SRC, 3),         \
        R##4 = ROR(SRC, 4),  R##5 = ROR(SRC, 5),  R##6 = ROR(SRC, 6),         \
        R##7 = ROR(SRC, 7),  R##8 = ROR(SRC, 8),  R##9 = ROR(SRC, 9),         \
        R##10 = ROR(SRC,10), R##11 = ROR(SRC,11), R##12 = ROR(SRC,12),        \
        R##13 = ROR(SRC,13), R##14 = ROR(SRC,14), R##15 = ROR(SRC,15);

// 16-FMA partial dot against rotation-ordered weights (4 chains + tree)
#define DOT16(Wr, SRC, R, dd)                                                 \
  float dd;                                                                   \
  { float q0 = Wr[0]*(SRC)  + Wr[4]*R##4;                                     \
    float q1 = Wr[1]*R##1   + Wr[5]*R##5;                                     \
    float q2 = Wr[2]*R##2   + Wr[6]*R##6;                                     \
    float q3 = Wr[3]*R##3   + Wr[7]*R##7;                                     \
    q0 += Wr[8]*R##8;   q1 += Wr[9]*R##9;                                     \
    q2 += Wr[10]*R##10; q3 += Wr[11]*R##11;                                   \
    q0 += Wr[12]*R##12; q1 += Wr[13]*R##13;                                   \
    q2 += Wr[14]*R##14; q3 += Wr[15]*R##15;                                   \
    dd = (q0 + q1) + (q2 + q3); }

// 16-lane ring reduction via rotate-adds (direction-agnostic), stays on VALU
#define RING16(v) { v += ROR(v,1); v += ROR(v,2); v += ROR(v,4); v += ROR(v,8); }

// ---------------------------------------------------------------------------
// k_main: fused prep + warm-up + loss. One wave per chunk of CLEN steps,
// warm-started WARM steps early (chunk 0 starts exactly from pi at t=0;
// Birkhoff contraction erases the uniform init for the rest — measured
// absmax 0.0 at WARM=32, so WARM=24 retains ~1e3x margin under threshold).
// K-SPLIT layout: lane l covers k-block h = l>>5 for output j = l&31.
// Step: 15 DPP rotations, 16 FMAs -> partial dot, one shfl_xor(32) combine.
// Loss loop keeps y UNNORMALIZED (true u, periodic 1/y_0 rescale); the
// S/N2 ring-reduce is scale-invariant side-band work with no consumer in
// the recursion chain, so it overlaps the next step's rotations.
// NCH=4000 -> ~3.9 waves/SIMD: chain (~200cy, 2 DS shuffles) is covered and
// the kernel runs at the VALU issue floor (~9us).
// ---------------------------------------------------------------------------
__global__ __launch_bounds__(256, 4) void k_main(
    const float* __restrict__ obs2, const float* __restrict__ obs1,
    const float* __restrict__ mean_p, const float* __restrict__ var_p,
    const float* __restrict__ bate_p, const float* __restrict__ pi_p,
    const float* __restrict__ aij, float* __restrict__ lossbuf)
{
  const int w = threadIdx.x >> 6, lane = threadIdx.x & 63;
  const int wv = blockIdx.x * WPB + w;
  const int i  = lane & 15;
  const int h  = lane >> 5;           // k-half this lane covers
  const int j  = lane & 31;           // this lane's output index
  const int kb = h * 16;              // k-block base

  __shared__ __align__(16) float Wsh[2][32][32];   // [sel][k][j]
  __shared__ float cts[WPB][MAXS + 3];

  // --- block-cooperative prep of W, W2 into LDS (once) ---
  {
    const int tid = threadIdx.x;
    const int jj = tid & 31, ig = tid >> 5;
    float vjq  = var_p[jj];
    float i2vq = 0.5f / vjq;
    float norm = rsqrtf(2.0f * PI_F * vjq);
    float Aj   = norm * expf(mean_p[jj] * i2vq);
    float bate = bate_p[0];
#pragma unroll
    for (int m = 0; m < 4; ++m) {
      int ii = ig * 4 + m;
      float Bij = expf(-bate * mean_p[ii] * i2vq);
      float wq = aij[ii * 32 + jj] * Aj * Bij;
      Wsh[0][ii][jj] = wq;
      Wsh[1][ii][jj] = wq * Aj * Bij;
    }
  }

  // --- per-lane exponent constants (j-indexed; halves duplicate) ---
  float vj  = var_p[j];
  float i2v = 0.5f / vj;
  float s_  = i2v;
#pragma unroll
  for (int o = 1; o < 32; o <<= 1) s_ += __shfl_xor(s_, o);
  const float i2vl = i2v * LOG2E;                      // true (loss)
  const float i2vc = (i2v - s_ * 0.03125f) * LOG2E;    // centered (warm)

  // --- stage cts for this wave's range ---
  const int t0 = wv * CLEN;
  const int tw = (t0 > WARM) ? (t0 - WARM) : 0;
  const int n  = t0 + CLEN - tw;
  const int warmsteps = t0 - tw;
  {
    float bate = bate_p[0];
    for (int l = lane; l < n; l += 64)
      cts[w][l] = obs2[tw + l] - bate * obs1[tw + l];
  }
  __syncthreads();   // Wsh ready (only barrier)

  // --- rotation direction probe (ROW_ROR direction made irrelevant) ---
  int dird;
  { int p = __builtin_amdgcn_mov_dpp(i, 0x121, 0xF, 0xF, false);
    dird = (p - i) & 15; }

  // --- rotation-ordered weights for this lane's k-block, output j ---
  float Wr[16], Vr[16];
#pragma unroll
  for (int N = 0; N < 16; ++N) {
    int kk = (i + N * dird) & 15;
    Wr[N] = Wsh[0][kb + kk][j];
    Vr[N] = Wsh[1][kb + kk][j];
  }

  // ysrc layout: lane must hold y_{kb + (l&15)}; from the j-indexed y this is
  // own y when (bit4 == h), else the xor-16 partner's value.
  const bool takeT = (((lane >> 4) & 1) ^ h) != 0;

  float y = (tw == 0) ? pi_p[j] : 0.03125f;
  float t = __shfl_xor(y, 16);
  float ysrc = takeT ? t : y;

  // ---- warm-up: centered u, W-dot only, unnormalized + periodic rescale ----
  for (int s = 0; s < warmsteps; ++s) {
    float ct = cts[w][s];
    float u  = exp2f(-ct * i2vc);
    ROTS(ysrc, a)
    DOT16(Wr, ysrc, a, pW)
    float dot = pW + __shfl_xor(pW, 32);
    y = u * dot;
    if ((s & 3) == 3)
      y *= __builtin_amdgcn_rcpf(__int_as_float(
             __builtin_amdgcn_readfirstlane(__float_as_int(y))));
    t = __shfl_xor(y, 16);
    ysrc = takeT ? t : y;
  }
  // ---- owned range (constant trip CLEN): true u, unnormalized y;
  //      loss reduce runs off the recursion chain ----
  float lossacc = 0.f;
#pragma unroll 5
  for (int q = 0; q < CLEN; ++q) {
    float ct = cts[w][warmsteps + q];
    float u  = exp2f(-ct * i2vl);
    ROTS(ysrc, a)
    DOT16(Wr, ysrc, a, pW)
    DOT16(Vr, ysrc, a, pV)
    float dotW = pW + __shfl_xor(pW, 32);
    float dotV = pV + __shfl_xor(pV, 32);
    float numj = u * dotW;             // next y (unnormalized)
    float n2j  = (u * u) * dotV;
    // --- recursion chain: only numj -> y -> ysrc ---
    y = numj;
    if ((q & 3) == 3)
      y *= __builtin_amdgcn_rcpf(__int_as_float(
             __builtin_amdgcn_readfirstlane(__float_as_int(y))));
    t = __shfl_xor(y, 16);
    ysrc = takeT ? t : y;
    // --- side-band loss reduce (no consumer in the chain) ---
    float red = h ? n2j : numj;
    RING16(red)
    red += __shfl_xor(red, 16);        // h=0 lanes: S ; h=1 lanes: N2
    float cross = __shfl_xor(red, 32);
    float S  = h ? cross : red;
    float N2 = h ? red   : cross;
    lossacc += N2 * __builtin_amdgcn_rcpf(S);
  }
  if (lane == 0) lossbuf[wv] = lossacc;
}

// ---------------------------------------------------------------------------
// Finish: sum NCH per-chunk losses -> out[0]
// ---------------------------------------------------------------------------
__global__ __launch_bounds__(256) void k_finish(const float* __restrict__ lb,
                                                float* __restrict__ out)
{
  const int tid = threadIdx.x;
  float v = 0.f;
  for (int l = tid; l < NCH; l += 256) v += lb[l];
#pragma unroll
  for (int o = 1; o < 64; o <<= 1) v += __shfl_xor(v, o);
  __shared__ float part[4];
  if ((tid & 63) == 0) part[tid >> 6] = v;
  __syncthreads();
  if (tid == 0) out[0] = part[0] + part[1] + part[2] + part[3];
}

extern "C" void kernel_launch(void* const* d_in, const int* in_sizes, int n_in,
                              void* d_out, int out_size, void* d_ws, size_t ws_size,
                              hipStream_t stream)
{
  (void)in_sizes; (void)n_in; (void)ws_size; (void)out_size;
  const float* obs2 = (const float*)d_in[0];
  const float* obs1 = (const float*)d_in[1];
  const float* mean = (const float*)d_in[2];
  const float* var  = (const float*)d_in[3];
  const float* bate = (const float*)d_in[4];
  const float* pi   = (const float*)d_in[5];
  const float* aij  = (const float*)d_in[6];
  float* lb  = (float*)d_ws;           // NCH floats, every slot written
  float* out = (float*)d_out;

  k_main  <<<NBLK, 256, 0, stream>>>(obs2, obs1, mean, var, bate, pi, aij, lb);
  k_finish<<<1,    256, 0, stream>>>(lb, out);
}